// Round 10
// baseline (163.726 us; speedup 1.0000x reference)
//
#include <hip/hip_runtime.h>
#include <hip/hip_bf16.h>
#include <cstdint>
#include <cstddef>

// ---------------------------------------------------------------------------
// Biaffine: out[b,x,y,o] = sum_ij in1[b,x,i] w1[i,o,j] in2[b,y,j] + lin terms
// B=32 S=1024 D=256 O=2.
//   prep : in1 -> in1b + lin1; in2 -> k-tiled in2t[b][kt][y][8] + lin2(+bias);
//          w1 -> w1t
//   gemm1: T[bx, oj] = in1b @ w1t^T      (16x16x32, BM=64)  [R4 version]
//   gemm2: BARRIER-FREE. A in registers, B-frags loaded global->VGPR from
//          k-tiled in2t (coalesced, L2-hot). No block barriers in the main
//          loop -> stores pace each wave independently; 8 waves/CU keep the
//          HBM write stream (the roofline) saturated.
// ---------------------------------------------------------------------------

typedef __bf16 bf16_t;
typedef __bf16 bf16x4 __attribute__((ext_vector_type(4)));
typedef __bf16 bf16x8 __attribute__((ext_vector_type(8)));
typedef float  f32x4  __attribute__((ext_vector_type(4)));
typedef float  f32x16 __attribute__((ext_vector_type(16)));

#define NB   32
#define NS   1024
#define ND   256
#define NM   (NB * NS)
#define NN1  512

__device__ __forceinline__ void gload_lds16(const void* g, void* l) {
  __builtin_amdgcn_global_load_lds(
      (__attribute__((address_space(1))) void*)g,
      (__attribute__((address_space(3))) void*)l, 16, 0, 0);
}

// ---------------------------------------------------------------------------
// prep: bid<8192: in1 cast + lin1 | bid<10240: in2 -> k-tiled + lin2 | w1t
// ---------------------------------------------------------------------------
__global__ __launch_bounds__(256) void prep_kernel(
    const float* __restrict__ in1, const float* __restrict__ in2,
    const float* __restrict__ w1,  const float* __restrict__ w2,
    bf16_t* __restrict__ in1b, bf16_t* __restrict__ in2t,
    bf16_t* __restrict__ w1t,  float* __restrict__ lin)
{
  __shared__ bf16_t sm[16][264];       // in2 bounce buffer (padded stride)
  int bid = blockIdx.x;
  int wave = threadIdx.x >> 6;
  int lane = threadIdx.x & 63;

  if (bid < 8192) {
    // ---- in1: 4 rows/block, cast + lin1 ----
    int r = bid * 4 + wave;
    float4 v = *(const float4*)(in1 + (size_t)r * ND + lane * 4);
    bf16x4 h;
    h[0] = (bf16_t)v.x; h[1] = (bf16_t)v.y; h[2] = (bf16_t)v.z; h[3] = (bf16_t)v.w;
    *(bf16x4*)(in1b + (size_t)r * ND + lane * 4) = h;

    int dbase = lane * 4;
    float a0 = v.x * w2[(dbase + 0) * 2 + 0] + v.y * w2[(dbase + 1) * 2 + 0]
             + v.z * w2[(dbase + 2) * 2 + 0] + v.w * w2[(dbase + 3) * 2 + 0];
    float a1 = v.x * w2[(dbase + 0) * 2 + 1] + v.y * w2[(dbase + 1) * 2 + 1]
             + v.z * w2[(dbase + 2) * 2 + 1] + v.w * w2[(dbase + 3) * 2 + 1];
    #pragma unroll
    for (int off = 32; off > 0; off >>= 1) {
      a0 += __shfl_down(a0, off, 64);
      a1 += __shfl_down(a1, off, 64);
    }
    if (lane == 0) {
      lin[(size_t)r * 2 + 0] = a0;
      lin[(size_t)r * 2 + 1] = a1;
    }
  } else if (bid < 10240) {
    // ---- in2: 16 rows/block via LDS bounce -> k-tiled in2t + lin2 ----
    int r0 = (bid - 8192) * 16;
    #pragma unroll
    for (int e = 0; e < 4; ++e) {
      int rl = wave * 4 + e;
      int rr = r0 + rl;
      float4 v = *(const float4*)(in2 + (size_t)rr * ND + lane * 4);
      bf16x4 h;
      h[0] = (bf16_t)v.x; h[1] = (bf16_t)v.y; h[2] = (bf16_t)v.z; h[3] = (bf16_t)v.w;
      *(bf16x4*)&sm[rl][lane * 4] = h;

      int dbase = ND + lane * 4;
      float a0 = v.x * w2[(dbase + 0) * 2 + 0] + v.y * w2[(dbase + 1) * 2 + 0]
               + v.z * w2[(dbase + 2) * 2 + 0] + v.w * w2[(dbase + 3) * 2 + 0];
      float a1 = v.x * w2[(dbase + 0) * 2 + 1] + v.y * w2[(dbase + 1) * 2 + 1]
               + v.z * w2[(dbase + 2) * 2 + 1] + v.w * w2[(dbase + 3) * 2 + 1];
      #pragma unroll
      for (int off = 32; off > 0; off >>= 1) {
        a0 += __shfl_down(a0, off, 64);
        a1 += __shfl_down(a1, off, 64);
      }
      if (lane == 0) {
        a0 += w2[2 * ND * 2 + 0]; a1 += w2[2 * ND * 2 + 1];   // bias
        lin[(size_t)(NM + rr) * 2 + 0] = a0;
        lin[(size_t)(NM + rr) * 2 + 1] = a1;
      }
    }
    __syncthreads();
    int b = r0 >> 10, ybase = r0 & 1023;
    #pragma unroll
    for (int p = 0; p < 2; ++p) {
      int c = p * 256 + threadIdx.x;
      int yloc = c & 15, kt = c >> 4;          // kt 0..31
      bf16x8 val = *(const bf16x8*)&sm[yloc][kt * 8];
      *(bf16x8*)(in2t + (((size_t)b * 32 + kt) * 1024 + ybase + yloc) * 8) = val;
    }
  } else {
    // ---- w1t ----
    int wb = bid - 10240;
    int t  = threadIdx.x;
    #pragma unroll
    for (int e = 0; e < 8; ++e) {
      int q  = wb * 2048 + e * 256 + t;
      int oj = q >> 8;
      int i  = q & 255;
      w1t[q] = (bf16_t)w1[i * NN1 + oj];
    }
  }
}

// ---------------------------------------------------------------------------
// gemm1 (R4 version): T[m,oj] = in1b[m,:] . w1t[oj,:]
// ---------------------------------------------------------------------------
__global__ __launch_bounds__(256, 3) void gemm1_kernel(
    const bf16_t* __restrict__ A, const bf16_t* __restrict__ Bt,
    bf16_t* __restrict__ T)
{
  __shared__ __align__(16) bf16_t Ap[64 * 256];
  __shared__ __align__(16) bf16_t Bc[2][128 * 32];

  int m0 = blockIdx.x * 64;
  int t = threadIdx.x, lane = t & 63, wid = t >> 6;
  int wm = (wid >> 1) * 32, wn = (wid & 1) * 64;

  #pragma unroll
  for (int i = 0; i < 8; ++i) {
    int unit = i * 256 + t;
    int row = unit >> 5;
    int c   = unit & 31;
    int cs  = c ^ (row & 7);
    gload_lds16(A + (size_t)(m0 + row) * ND + cs * 8, (char*)Ap + unit * 16);
  }
  #pragma unroll
  for (int i = 0; i < 2; ++i) {
    int unit = i * 256 + t;
    int row = unit >> 2, c = unit & 3, cs = c ^ (row & 3);
    gload_lds16(Bt + (size_t)row * ND + cs * 8, (char*)Bc[0] + unit * 16);
  }
  __syncthreads();

  f32x4 acc[2][4] = {};

  for (int s = 0; s < 32; ++s) {
    if (s + 1 < 32) {
      int nt = (s + 1) >> 3, j0 = ((s + 1) & 7) * 32;
      bf16_t* dst = (bf16_t*)Bc[(s + 1) & 1];
      #pragma unroll
      for (int i = 0; i < 2; ++i) {
        int unit = i * 256 + t;
        int row = unit >> 2, c = unit & 3, cs = c ^ (row & 3);
        gload_lds16(Bt + (size_t)(nt * 128 + row) * ND + j0 + cs * 8,
                    (char*)dst + unit * 16);
      }
    }
    const bf16_t* Bcur = Bc[s & 1];
    bf16x8 bfr[4];
    #pragma unroll
    for (int ni = 0; ni < 4; ++ni) {
      int r = wn + ni * 16 + (lane & 15);
      int cp = (lane >> 4) ^ (r & 3);
      bfr[ni] = *(const bf16x8*)&Bcur[r * 32 + cp * 8];
    }
    #pragma unroll
    for (int mi = 0; mi < 2; ++mi) {
      int r = wm + mi * 16 + (lane & 15);
      int cl = (s & 7) * 4 + (lane >> 4);
      int cp = cl ^ (r & 7);
      bf16x8 af = *(const bf16x8*)&Ap[r * 256 + cp * 8];
      #pragma unroll
      for (int ni = 0; ni < 4; ++ni)
        acc[mi][ni] = __builtin_amdgcn_mfma_f32_16x16x32_bf16(
            af, bfr[ni], acc[mi][ni], 0, 0, 0);
    }
    if ((s & 7) == 7) {
      int nt = s >> 3;
      #pragma unroll
      for (int mi = 0; mi < 2; ++mi) {
        int row = m0 + wm + mi * 16 + ((lane >> 4) << 2);
        #pragma unroll
        for (int ni = 0; ni < 4; ++ni) {
          int col = nt * 128 + wn + ni * 16 + (lane & 15);
          #pragma unroll
          for (int r_ = 0; r_ < 4; ++r_)
            T[(size_t)(row + r_) * NN1 + col] = (bf16_t)acc[mi][ni][r_];
          acc[mi][ni] = (f32x4){0.f, 0.f, 0.f, 0.f};
        }
      }
    }
    __syncthreads();
  }
}

// ---------------------------------------------------------------------------
// gemm2 (barrier-free): per (b, 64-row x-tile). A-panel staged once to LDS
// (gload_lds, swizzled) -> af[2][16] registers. lin staged to LDS. ONE
// __syncthreads, then: 8 y-tiles x {16 ks: 2 coalesced global B-frag loads
// + 4 MFMA 32x32x16} + epilogue (LDS lin + 32 float2 stores). No barriers,
// no LDS B-ring -> waves run free; stores pace the kernel at HBM write BW.
// ---------------------------------------------------------------------------
__global__ __launch_bounds__(256, 2) void gemm2_kernel(
    const bf16_t* __restrict__ Tm, const bf16_t* __restrict__ in2t,
    const float* __restrict__ lin, float* __restrict__ out)
{
  // 64 KB A-stage + 512 B lin1 + 8 KB lin2
  __shared__ __align__(16) char smem[65536 + 512 + 8192];

  // XCD-aware bijective swizzle: 512 blocks, 64/XCD -> 4 batches per XCD
  int blk = (blockIdx.x & 7) * 64 + (blockIdx.x >> 3);
  int b   = blk >> 4;
  int x0  = (blk & 15) * 64;
  const bf16_t* Tb = Tm   + (size_t)b * NS * NN1;
  const bf16_t* I2 = in2t + (size_t)b * 32 * 1024 * 8;   // [kt][y][8]

  int t = threadIdx.x, lane = t & 63, wid = t >> 6;
  int wx = (wid >> 1) * 32;        // x-slot: 0 or 32
  int wy = (wid & 1) * 64;         // y-slot within 128-wide y-tile: 0 or 64
  int l31 = lane & 31, lhi = lane >> 5;

  // ---- stage A-panel 64x512 (swizzled) + lin, one burst ----
  bf16_t* Ap = (bf16_t*)smem;
  #pragma unroll
  for (int i = 0; i < 16; ++i) {
    int unit = i * 256 + t;
    int row = unit >> 6;
    int c   = unit & 63;
    int cs  = c ^ (row & 7);
    gload_lds16(Tb + (size_t)(x0 + row) * NN1 + cs * 8, (char*)Ap + unit * 16);
  }
  if (t < 32)
    gload_lds16(lin + ((size_t)b * NS + x0) * 2 + t * 4, smem + 65536 + t * 16);
  #pragma unroll
  for (int i = 0; i < 2; ++i) {
    int u = i * 256 + t;
    gload_lds16(lin + ((size_t)NM + (size_t)b * NS) * 2 + u * 4,
                smem + 66048 + u * 16);
  }
  __syncthreads();     // the ONLY block barrier

  // ---- prefill A-frags: af[o][ks], 32x bf16x8 = 128 VGPR ----
  bf16x8 af[2][16];
  {
    int row = wx + l31;
    #pragma unroll
    for (int o = 0; o < 2; ++o)
      #pragma unroll
      for (int ks = 0; ks < 16; ++ks) {
        int ls = o * 32 + ks * 2 + lhi;
        int sm = ls ^ (row & 7);
        af[o][ks] = *(const bf16x8*)&Ap[(row * 64 + sm) * 8];
      }
  }

  f32x16 acc[2][2] = {};   // [ni][o]
  float2* outb = (float2*)(out + (size_t)b * NS * NS * 2);
  const float2* l1s = (const float2*)(smem + 65536);
  const float2* l2s = (const float2*)(smem + 66048);
  int lrow_base = wx + 4 * lhi;

  for (int yt = 0; yt < 8; ++yt) {
    int ybase = yt * 128 + wy + l31;
    // 16 ks: B-frags straight from L2-resident k-tiled in2t
    #pragma unroll
    for (int ks = 0; ks < 16; ++ks) {
      int kt = ks * 2 + lhi;
      const bf16_t* src = I2 + ((size_t)kt * 1024 + ybase) * 8;
      bf16x8 b0 = *(const bf16x8*)(src);
      bf16x8 b1 = *(const bf16x8*)(src + 32 * 8);
      acc[0][0] = __builtin_amdgcn_mfma_f32_32x32x16_bf16(af[0][ks], b0, acc[0][0], 0, 0, 0);
      acc[0][1] = __builtin_amdgcn_mfma_f32_32x32x16_bf16(af[1][ks], b0, acc[0][1], 0, 0, 0);
      acc[1][0] = __builtin_amdgcn_mfma_f32_32x32x16_bf16(af[0][ks], b1, acc[1][0], 0, 0, 0);
      acc[1][1] = __builtin_amdgcn_mfma_f32_32x32x16_bf16(af[1][ks], b1, acc[1][1], 0, 0, 0);
    }
    // epilogue: LDS lin + stores (no barrier; wave-local pacing)
    {
      int y0 = yt * 128;
      float2 l2[2];
      #pragma unroll
      for (int ni = 0; ni < 2; ++ni) l2[ni] = l2s[y0 + wy + ni * 32 + l31];
      #pragma unroll
      for (int r = 0; r < 16; ++r) {
        int lrow = lrow_base + (r & 3) + 8 * (r >> 2);
        float2 l1 = l1s[lrow];
        int row = x0 + lrow;
        #pragma unroll
        for (int ni = 0; ni < 2; ++ni) {
          int col = y0 + wy + ni * 32 + l31;
          float2 v;
          v.x = acc[ni][0][r] + l1.x + l2[ni].x;
          v.y = acc[ni][1][r] + l1.y + l2[ni].y;
          outb[(size_t)row * NS + col] = v;
        }
      }
      acc[0][0] = (f32x16)(0.f); acc[0][1] = (f32x16)(0.f);
      acc[1][0] = (f32x16)(0.f); acc[1][1] = (f32x16)(0.f);
    }
  }
}

// ---------------------------------------------------------------------------
extern "C" void kernel_launch(void* const* d_in, const int* in_sizes, int n_in,
                              void* d_out, int out_size, void* d_ws, size_t ws_size,
                              hipStream_t stream) {
  const float* in1 = (const float*)d_in[0];
  const float* in2 = (const float*)d_in[1];
  const float* w1  = (const float*)d_in[2];
  const float* w2  = (const float*)d_in[3];
  float* out = (float*)d_out;

  char* ws = (char*)d_ws;
  bf16_t* in1b = (bf16_t*)(ws);                                   // 16 MiB
  bf16_t* in2t = (bf16_t*)(ws + (16u << 20));                     // 16 MiB
  bf16_t* w1t  = (bf16_t*)(ws + (32u << 20));                     // 256 KiB
  float*  lin  = (float*) (ws + (32u << 20) + (256u << 10));      // 512 KiB
  bf16_t* T    = (bf16_t*)(ws + (33u << 20));                     // 32 MiB

  prep_kernel<<<10304, 256, 0, stream>>>(in1, in2, w1, w2, in1b, in2t, w1t, lin);
  gemm1_kernel<<<512, 256, 0, stream>>>(in1b, w1t, T);
  gemm2_kernel<<<512, 256, 0, stream>>>(T, in2t, lin, out);
}

// Round 11
// 119.712 us; speedup vs baseline: 1.3677x; 1.3677x over previous
//
#include <hip/hip_runtime.h>
#include <hip/hip_bf16.h>
#include <cstdint>
#include <cstddef>

// ---------------------------------------------------------------------------
// Biaffine: out[b,x,y,o] = sum_ij in1[b,x,i] w1[i,o,j] in2[b,y,j] + lin terms
// B=32 S=1024 D=256 O=2.  [EXACT R4 resubmit — reproducibility anchor]
//   prep : cast inputs to bf16, lin terms, w1 transpose
//   gemm1: T[bx, oj] = in1b @ w1t^T      (16x16x32, BM=64)
//   gemm2: out = T . in2b + lin          (32x32x16, A in REGISTERS (128 VGPR),
//                                         B streamed 128y x 64k dbuf, LDS
//                                         union 64KB, 2 blocks/CU, XCD swizzle)
// ---------------------------------------------------------------------------

typedef __bf16 bf16_t;
typedef __bf16 bf16x4 __attribute__((ext_vector_type(4)));
typedef __bf16 bf16x8 __attribute__((ext_vector_type(8)));
typedef float  f32x4  __attribute__((ext_vector_type(4)));
typedef float  f32x16 __attribute__((ext_vector_type(16)));

#define NB   32
#define NS   1024
#define ND   256
#define NM   (NB * NS)
#define NN1  512

__device__ __forceinline__ void gload_lds16(const void* g, void* l) {
  __builtin_amdgcn_global_load_lds(
      (__attribute__((address_space(1))) void*)g,
      (__attribute__((address_space(3))) void*)l, 16, 0, 0);
}

// ---------------------------------------------------------------------------
// prep
// ---------------------------------------------------------------------------
__global__ __launch_bounds__(256) void prep_kernel(
    const float* __restrict__ in1, const float* __restrict__ in2,
    const float* __restrict__ w1,  const float* __restrict__ w2,
    bf16_t* __restrict__ in1b, bf16_t* __restrict__ in2b,
    bf16_t* __restrict__ w1t,  float* __restrict__ lin)
{
  int bid = blockIdx.x;
  if (bid < 16384) {
    int wave = threadIdx.x >> 6;
    int lane = threadIdx.x & 63;
    int r  = bid * 4 + wave;
    int is2 = (r >= NM) ? 1 : 0;
    int lr = r & (NM - 1);
    const float* src = is2 ? in2 : in1;
    bf16_t*      dst = is2 ? in2b : in1b;

    float4 v = *(const float4*)(src + (size_t)lr * ND + lane * 4);
    bf16x4 h;
    h[0] = (bf16_t)v.x; h[1] = (bf16_t)v.y; h[2] = (bf16_t)v.z; h[3] = (bf16_t)v.w;
    *(bf16x4*)(dst + (size_t)lr * ND + lane * 4) = h;

    int dbase = is2 * ND + lane * 4;
    float a0 = v.x * w2[(dbase + 0) * 2 + 0] + v.y * w2[(dbase + 1) * 2 + 0]
             + v.z * w2[(dbase + 2) * 2 + 0] + v.w * w2[(dbase + 3) * 2 + 0];
    float a1 = v.x * w2[(dbase + 0) * 2 + 1] + v.y * w2[(dbase + 1) * 2 + 1]
             + v.z * w2[(dbase + 2) * 2 + 1] + v.w * w2[(dbase + 3) * 2 + 1];
    #pragma unroll
    for (int off = 32; off > 0; off >>= 1) {
      a0 += __shfl_down(a0, off, 64);
      a1 += __shfl_down(a1, off, 64);
    }
    if (lane == 0) {
      if (is2) { a0 += w2[2 * ND * 2 + 0]; a1 += w2[2 * ND * 2 + 1]; }
      lin[r * 2 + 0] = a0;
      lin[r * 2 + 1] = a1;
    }
  } else {
    int wb = bid - 16384;
    int t  = threadIdx.x;
    #pragma unroll
    for (int e = 0; e < 8; ++e) {
      int q  = wb * 2048 + e * 256 + t;
      int oj = q >> 8;
      int i  = q & 255;
      w1t[q] = (bf16_t)w1[i * NN1 + oj];
    }
  }
}

// ---------------------------------------------------------------------------
// gemm1: T[m,oj] = in1b[m,:] . w1t[oj,:]
// ---------------------------------------------------------------------------
__global__ __launch_bounds__(256, 3) void gemm1_kernel(
    const bf16_t* __restrict__ A, const bf16_t* __restrict__ Bt,
    bf16_t* __restrict__ T)
{
  __shared__ __align__(16) bf16_t Ap[64 * 256];
  __shared__ __align__(16) bf16_t Bc[2][128 * 32];

  int m0 = blockIdx.x * 64;
  int t = threadIdx.x, lane = t & 63, wid = t >> 6;
  int wm = (wid >> 1) * 32, wn = (wid & 1) * 64;

  #pragma unroll
  for (int i = 0; i < 8; ++i) {
    int unit = i * 256 + t;
    int row = unit >> 5;
    int c   = unit & 31;
    int cs  = c ^ (row & 7);
    gload_lds16(A + (size_t)(m0 + row) * ND + cs * 8, (char*)Ap + unit * 16);
  }
  #pragma unroll
  for (int i = 0; i < 2; ++i) {
    int unit = i * 256 + t;
    int row = unit >> 2, c = unit & 3, cs = c ^ (row & 3);
    gload_lds16(Bt + (size_t)row * ND + cs * 8, (char*)Bc[0] + unit * 16);
  }
  __syncthreads();

  f32x4 acc[2][4] = {};

  for (int s = 0; s < 32; ++s) {
    if (s + 1 < 32) {
      int nt = (s + 1) >> 3, j0 = ((s + 1) & 7) * 32;
      bf16_t* dst = (bf16_t*)Bc[(s + 1) & 1];
      #pragma unroll
      for (int i = 0; i < 2; ++i) {
        int unit = i * 256 + t;
        int row = unit >> 2, c = unit & 3, cs = c ^ (row & 3);
        gload_lds16(Bt + (size_t)(nt * 128 + row) * ND + j0 + cs * 8,
                    (char*)dst + unit * 16);
      }
    }
    const bf16_t* Bcur = Bc[s & 1];
    bf16x8 bfr[4];
    #pragma unroll
    for (int ni = 0; ni < 4; ++ni) {
      int r = wn + ni * 16 + (lane & 15);
      int cp = (lane >> 4) ^ (r & 3);
      bfr[ni] = *(const bf16x8*)&Bcur[r * 32 + cp * 8];
    }
    #pragma unroll
    for (int mi = 0; mi < 2; ++mi) {
      int r = wm + mi * 16 + (lane & 15);
      int cl = (s & 7) * 4 + (lane >> 4);
      int cp = cl ^ (r & 7);
      bf16x8 af = *(const bf16x8*)&Ap[r * 256 + cp * 8];
      #pragma unroll
      for (int ni = 0; ni < 4; ++ni)
        acc[mi][ni] = __builtin_amdgcn_mfma_f32_16x16x32_bf16(
            af, bfr[ni], acc[mi][ni], 0, 0, 0);
    }
    if ((s & 7) == 7) {
      int nt = s >> 3;
      #pragma unroll
      for (int mi = 0; mi < 2; ++mi) {
        int row = m0 + wm + mi * 16 + ((lane >> 4) << 2);
        #pragma unroll
        for (int ni = 0; ni < 4; ++ni) {
          int col = nt * 128 + wn + ni * 16 + (lane & 15);
          #pragma unroll
          for (int r_ = 0; r_ < 4; ++r_)
            T[(size_t)(row + r_) * NN1 + col] = (bf16_t)acc[mi][ni][r_];
          acc[mi][ni] = (f32x4){0.f, 0.f, 0.f, 0.f};
        }
      }
    }
    __syncthreads();
  }
}

// ---------------------------------------------------------------------------
// gemm2: per (b, 64-row x-tile). A = T[x0:x0+64, 0:512] held in REGISTERS
// (per wave: 32 rows x K256 x o2 = 32 bf16x8 frags = 128 VGPR).
// B = in2b streamed [128y x 64k] chunks (16 KB, dbuf in LDS union with the
// one-shot A staging panel). 32 steps = 8 y-tiles x 4 k-chunks.
// MFMA 32x32x16. 64 KB LDS -> 2 blocks/CU. Waves: 2x (32 x-rows) x 2y (64 y).
// ---------------------------------------------------------------------------
__global__ __launch_bounds__(256, 2) void gemm2_kernel(
    const bf16_t* __restrict__ Tm, const bf16_t* __restrict__ in2b,
    const float* __restrict__ lin, float* __restrict__ out)
{
  __shared__ __align__(16) char smem[65536];
  bf16_t* Ap = (bf16_t*)smem;                 // 64x512 bf16, one-shot staging
  bf16_t* Bbuf[2] = { (bf16_t*)smem, (bf16_t*)(smem + 16384) };  // after prefill

  // XCD-aware bijective swizzle: 512 blocks, 64/XCD -> 4 batches per XCD
  int blk = (blockIdx.x & 7) * 64 + (blockIdx.x >> 3);
  int b   = blk >> 4;
  int x0  = (blk & 15) * 64;
  const bf16_t* Tb = Tm   + (size_t)b * NS * NN1;
  const bf16_t* Ib = in2b + (size_t)b * NS * ND;

  int t = threadIdx.x, lane = t & 63, wid = t >> 6;
  int wx = (wid >> 1) * 32;        // x-slot: 0 or 32
  int wy = (wid & 1) * 64;         // y-slot within 128-chunk: 0 or 64
  int l31 = lane & 31, lhi = lane >> 5;

  // ---- stage A-panel (swizzled): 4096 16B units, 64 slots/row ----
  #pragma unroll
  for (int i = 0; i < 16; ++i) {
    int unit = i * 256 + t;
    int row = unit >> 6;
    int c   = unit & 63;
    int cs  = c ^ (row & 7);
    gload_lds16(Tb + (size_t)(x0 + row) * NN1 + cs * 8, (char*)Ap + unit * 16);
  }
  __syncthreads();

  // ---- prefill A-frags into registers: af[o][ks], 32x bf16x8 = 128 VGPR ----
  bf16x8 af[2][16];
  {
    int row = wx + l31;
    #pragma unroll
    for (int o = 0; o < 2; ++o)
      #pragma unroll
      for (int ks = 0; ks < 16; ++ks) {
        int ls = o * 32 + ks * 2 + lhi;
        int sm = ls ^ (row & 7);
        af[o][ks] = *(const bf16x8*)&Ap[(row * 64 + sm) * 8];
      }
  }
  __syncthreads();   // everyone done reading Ap before B overwrites it

  // ---- stage B chunk 0 (yi=0,kc=0): 1024 units, 8 slots/row, ^row&7 ----
  #pragma unroll
  for (int i = 0; i < 4; ++i) {
    int u = i * 256 + t;
    int row = u >> 3, sm = u & 7;
    int cs = sm ^ (row & 7);
    gload_lds16(Ib + (size_t)row * ND + cs * 8, (char*)Bbuf[0] + u * 16);
  }
  __syncthreads();

  f32x16 acc[2][2] = {};   // [ni][o]
  float2* outb = (float2*)(out + (size_t)b * NS * NS * 2);
  const float2* l1p = (const float2*)(lin + (size_t)b * NS * 2);
  const float2* l2p = (const float2*)(lin + (size_t)(NM + b * NS) * 2);

  for (int yi = 0; yi < 8; ++yi) {
    #pragma unroll
    for (int kc = 0; kc < 4; ++kc) {
      // prefetch next chunk (parity (kc+1)&1 is compile-time)
      if (yi < 7 || kc < 3) {
        int c1 = yi * 4 + kc + 1;
        int yn = c1 >> 2, kn = (c1 & 3) * 64;
        char* dst = (char*)Bbuf[(kc + 1) & 1];
        #pragma unroll
        for (int i = 0; i < 4; ++i) {
          int u = i * 256 + t;
          int row = u >> 3, sm = u & 7;
          int cs = sm ^ (row & 7);
          gload_lds16(Ib + (size_t)(yn * 128 + row) * ND + kn + cs * 8,
                      dst + u * 16);
        }
      }
      const bf16_t* Bp = Bbuf[kc & 1];
      #pragma unroll
      for (int ni = 0; ni < 2; ++ni) {
        int row = wy + ni * 32 + l31;
        #pragma unroll
        for (int k2 = 0; k2 < 4; ++k2) {
          int ls = k2 * 2 + lhi;
          int sm = ls ^ (row & 7);
          bf16x8 bf = *(const bf16x8*)&Bp[(row * 8 + sm) * 8];
          acc[ni][0] = __builtin_amdgcn_mfma_f32_32x32x16_bf16(
              af[0][kc * 4 + k2], bf, acc[ni][0], 0, 0, 0);
          acc[ni][1] = __builtin_amdgcn_mfma_f32_32x32x16_bf16(
              af[1][kc * 4 + k2], bf, acc[ni][1], 0, 0, 0);
        }
      }
      if (kc == 3) {
        // epilogue for this y-tile of 128
        int y0 = yi * 128;
        float2 l2[2];
        #pragma unroll
        for (int ni = 0; ni < 2; ++ni) l2[ni] = l2p[y0 + wy + ni * 32 + l31];
        int xr = x0 + wx + 4 * lhi;
        #pragma unroll
        for (int r = 0; r < 16; ++r) {
          int row = xr + (r & 3) + 8 * (r >> 2);
          float2 l1 = l1p[row];
          #pragma unroll
          for (int ni = 0; ni < 2; ++ni) {
            int col = y0 + wy + ni * 32 + l31;
            float2 v;
            v.x = acc[ni][0][r] + l1.x + l2[ni].x;
            v.y = acc[ni][1][r] + l1.y + l2[ni].y;
            outb[(size_t)row * NS + col] = v;
          }
        }
        acc[0][0] = (f32x16)(0.f); acc[0][1] = (f32x16)(0.f);
        acc[1][0] = (f32x16)(0.f); acc[1][1] = (f32x16)(0.f);
      }
      __syncthreads();
    }
  }
}

// ---------------------------------------------------------------------------
extern "C" void kernel_launch(void* const* d_in, const int* in_sizes, int n_in,
                              void* d_out, int out_size, void* d_ws, size_t ws_size,
                              hipStream_t stream) {
  const float* in1 = (const float*)d_in[0];
  const float* in2 = (const float*)d_in[1];
  const float* w1  = (const float*)d_in[2];
  const float* w2  = (const float*)d_in[3];
  float* out = (float*)d_out;

  char* ws = (char*)d_ws;
  bf16_t* in1b = (bf16_t*)(ws);                                   // 16 MiB
  bf16_t* in2b = (bf16_t*)(ws + (16u << 20));                     // 16 MiB
  bf16_t* w1t  = (bf16_t*)(ws + (32u << 20));                     // 256 KiB
  float*  lin  = (float*) (ws + (32u << 20) + (256u << 10));      // 512 KiB
  bf16_t* T    = (bf16_t*)(ws + (33u << 20));                     // 32 MiB

  prep_kernel<<<16448, 256, 0, stream>>>(in1, in2, w1, w2, in1b, in2b, w1t, lin);
  gemm1_kernel<<<512, 256, 0, stream>>>(in1b, w1t, T);
  gemm2_kernel<<<512, 256, 0, stream>>>(T, in2b, lin, out);
}